// Round 1
// baseline (389.560 us; speedup 1.0000x reference)
//
#include <hip/hip_runtime.h>
#include <cstdint>

#define D_MODEL 1024
#define D_INNER 2048
#define LSEQ    4096
#define BATCH   2
#define M_ROWS  (BATCH * LSEQ)   // 8192
#define CHUNK   128
#define NCHUNK  (LSEQ / CHUNK)   // 32

typedef unsigned short u16;
typedef __bf16 bf16x8 __attribute__((ext_vector_type(8)));
typedef float f32x4 __attribute__((ext_vector_type(4)));
typedef u16 u16x4 __attribute__((ext_vector_type(4)));

__device__ __forceinline__ u16 f2bf(float f) {
  union { float f; unsigned u; } x; x.f = f;
  unsigned u = x.u;
  unsigned r = (u + 0x7FFFu + ((u >> 16) & 1u)) >> 16;
  return (u16)r;
}
__device__ __forceinline__ float bf2f(u16 h) {
  union { unsigned u; float f; } x; x.u = ((unsigned)h) << 16;
  return x.f;
}
__device__ __forceinline__ float sigmoidf_(float v) { return 1.0f / (1.0f + expf(-v)); }
__device__ __forceinline__ float siluf_(float v)    { return v / (1.0f + expf(-v)); }

__device__ __forceinline__ void gl_lds16(const void* g, void* l) {
  __builtin_amdgcn_global_load_lds(
      (const __attribute__((address_space(1))) void*)g,
      (__attribute__((address_space(3))) void*)l, 16, 0, 0);
}

// ---------------- cast fp32 -> bf16 (vectorized) ----------------
__global__ void __launch_bounds__(256)
cast_bf16_kernel(const float* __restrict__ in, u16* __restrict__ out, int n4) {
  int i = blockIdx.x * 256 + threadIdx.x;
  if (i < n4) {
    float4 v = ((const float4*)in)[i];
    u16x4 o;
    o.x = f2bf(v.x); o.y = f2bf(v.y); o.z = f2bf(v.z); o.w = f2bf(v.w);
    ((u16x4*)out)[i] = o;
  }
}

// ---------------- LayerNorm -> bf16 ----------------
__global__ void __launch_bounds__(256)
ln_kernel(const float* __restrict__ x, const float* __restrict__ w,
          const float* __restrict__ b, u16* __restrict__ xn) {
  const int row = blockIdx.x;
  const int t = threadIdx.x;
  const float4 v = ((const float4*)(x + (size_t)row * D_MODEL))[t];
  float s  = v.x + v.y + v.z + v.w;
  float ss = v.x * v.x + v.y * v.y + v.z * v.z + v.w * v.w;
#pragma unroll
  for (int o = 32; o > 0; o >>= 1) {
    s  += __shfl_xor(s, o);
    ss += __shfl_xor(ss, o);
  }
  __shared__ float red[8];
  const int wid = t >> 6, lane = t & 63;
  if (lane == 0) { red[wid] = s; red[4 + wid] = ss; }
  __syncthreads();
  s  = red[0] + red[1] + red[2] + red[3];
  ss = red[4] + red[5] + red[6] + red[7];
  const float mu  = s * (1.0f / D_MODEL);
  const float var = ss * (1.0f / D_MODEL) - mu * mu;
  const float rs  = rsqrtf(var + 1e-5f);
  const float4 wv = ((const float4*)w)[t];
  const float4 bv = ((const float4*)b)[t];
  u16x4 o4;
  o4.x = f2bf((v.x - mu) * rs * wv.x + bv.x);
  o4.y = f2bf((v.y - mu) * rs * wv.y + bv.y);
  o4.z = f2bf((v.z - mu) * rs * wv.z + bv.z);
  o4.w = f2bf((v.w - mu) * rs * wv.w + bv.w);
  ((u16x4*)(xn + (size_t)row * D_MODEL))[t] = o4;
}

// ---------------- bf16 GEMM, C = A(MxK) * B(NxK)^T, m97 structure ----------------
// EPI 0: split write: col<D_INNER -> x_inner bf16 ; col>=D_INNER -> silu -> sz bf16
// EPI 1: a = sigmoid(c + bias[col]) -> fp32
// EPI 2: out = c + residual[row,col] -> fp32
template<int EPI>
__global__ void __launch_bounds__(256)
gemm_bt(const u16* __restrict__ A, const u16* __restrict__ Bm,
        int M, int N, int K,
        const float* __restrict__ ef, float* __restrict__ of,
        u16* __restrict__ ob0, u16* __restrict__ ob1) {
  __shared__ __align__(128) char lds[16384];
  const int tid = threadIdx.x;
  const int wid = tid >> 6, lane = tid & 63;
  const int nbx = N >> 7;
  const int nwg = nbx * (M >> 7);
  const int bid = blockIdx.x;
  const int cpx = nwg >> 3;                       // nwg % 8 == 0 for all our shapes
  const int swz = (bid & 7) * cpx + (bid >> 3);   // XCD-aware swizzle
  const int bx = swz % nbx, by = swz / nbx;
  const size_t m0 = (size_t)by << 7, n0 = (size_t)bx << 7;

  const size_t rbA = (size_t)K * 2;  // row bytes (bf16)
  const char* gA = (const char*)A + (m0 + (size_t)((wid << 4) + (lane >> 2))) * rbA + ((lane & 3) << 4);
  const char* gB = (const char*)Bm + (n0 + (size_t)((wid << 4) + (lane >> 2))) * rbA + ((lane & 3) << 4);
  const size_t rowjmp = (size_t)64 * rbA;

  char* sAw = lds + (wid << 10);           // wave-uniform LDS dst
  char* sBw = lds + 8192 + (wid << 10);

  const int wr = wid >> 1, wc = wid & 1;
  const char* pa = lds + ((wr << 6) + (lane & 15)) * 64 + ((lane >> 4) << 4);
  const char* pb = lds + 8192 + ((wc << 6) + (lane & 15)) * 64 + ((lane >> 4) << 4);

  f32x4 acc[4][4] = {};
  const int nk = K >> 5;
  for (int kt = 0; kt < nk; ++kt) {
    gl_lds16(gA,          sAw);
    gl_lds16(gA + rowjmp, sAw + 4096);
    gl_lds16(gB,          sBw);
    gl_lds16(gB + rowjmp, sBw + 4096);
    gA += 64; gB += 64;
    __syncthreads();   // drains vmcnt -> LDS tile ready
    bf16x8 af[4], bfr[4];
#pragma unroll
    for (int i = 0; i < 4; ++i) af[i]  = *(const bf16x8*)(pa + (i << 10));
#pragma unroll
    for (int i = 0; i < 4; ++i) bfr[i] = *(const bf16x8*)(pb + (i << 10));
#pragma unroll
    for (int mi = 0; mi < 4; ++mi)
#pragma unroll
      for (int ni = 0; ni < 4; ++ni)
        acc[mi][ni] = __builtin_amdgcn_mfma_f32_16x16x32_bf16(af[mi], bfr[ni], acc[mi][ni], 0, 0, 0);
    __syncthreads();   // all waves done reading before next stage
  }

  const int c0 = lane & 15;
  const int r0 = (lane >> 4) << 2;
#pragma unroll
  for (int mi = 0; mi < 4; ++mi) {
#pragma unroll
    for (int ni = 0; ni < 4; ++ni) {
#pragma unroll
      for (int r = 0; r < 4; ++r) {
        const size_t row = m0 + (size_t)((wr << 6) + (mi << 4) + r0 + r);
        const size_t col = n0 + (size_t)((wc << 6) + (ni << 4) + c0);
        const float v = acc[mi][ni][r];
        if (EPI == 0) {
          if (col < (size_t)D_INNER) ob0[row * D_INNER + col] = f2bf(v);
          else                       ob1[row * D_INNER + (col - D_INNER)] = f2bf(siluf_(v));
        } else if (EPI == 1) {
          of[row * (size_t)N + col] = sigmoidf_(v + ef[col]);
        } else {
          of[row * (size_t)N + col] = v + ef[row * (size_t)N + col];
        }
      }
    }
  }
}

// ---------------- causal depthwise conv (K=4) + SiLU ----------------
__global__ void __launch_bounds__(256)
conv_silu_kernel(const u16* __restrict__ xin, const float* __restrict__ cw,
                 const float* __restrict__ cb, u16* __restrict__ xc) {
  const int c   = blockIdx.x * 256 + threadIdx.x;
  const int l0  = blockIdx.y * 8;
  const int bat = blockIdx.z;
  const size_t base = ((size_t)bat * LSEQ) * D_INNER + c;
  const float w0 = cw[c * 4 + 0], w1 = cw[c * 4 + 1], w2 = cw[c * 4 + 2], w3 = cw[c * 4 + 3];
  const float bb = cb[c];
  float v[11];
#pragma unroll
  for (int i = 0; i < 11; ++i) {
    const int l = l0 - 3 + i;
    v[i] = (l >= 0) ? bf2f(xin[base + (size_t)l * D_INNER]) : 0.0f;
  }
#pragma unroll
  for (int r = 0; r < 8; ++r) {
    const float acc = bb + w0 * v[r] + w1 * v[r + 1] + w2 * v[r + 2] + w3 * v[r + 3];
    xc[base + (size_t)(l0 + r) * D_INNER] = f2bf(siluf_(acc));
  }
}

// ---------------- chunked scan: pass A (per-chunk composition) ----------------
__global__ void __launch_bounds__(256)
scan_a_kernel(const float* __restrict__ a, const u16* __restrict__ xc,
              float* __restrict__ cA, float* __restrict__ cB) {
  const int c   = blockIdx.x * 256 + threadIdx.x;
  const int ch  = blockIdx.y;
  const int bat = blockIdx.z;
  size_t idx = ((size_t)bat * LSEQ + (size_t)ch * CHUNK) * D_INNER + c;
  float pA = 1.0f, hB = 0.0f;
  for (int t = 0; t < CHUNK; ++t) {
    const float av = a[idx];
    const float bv = (1.0f - av) * bf2f(xc[idx]);
    pA *= av;
    hB = av * hB + bv;
    idx += D_INNER;
  }
  const size_t o = ((size_t)bat * NCHUNK + ch) * D_INNER + c;
  cA[o] = pA; cB[o] = hB;
}

// ---------------- pass B: serial scan over chunk summaries ----------------
__global__ void __launch_bounds__(256)
scan_b_kernel(const float* __restrict__ cA, const float* __restrict__ cB,
              float* __restrict__ carry) {
  const int tid = blockIdx.x * 256 + threadIdx.x;  // BATCH*D_INNER = 4096
  const int bat = tid >> 11;
  const int c   = tid & (D_INNER - 1);
  float h = 0.0f;
  const size_t base = (size_t)bat * NCHUNK * D_INNER + c;
  for (int i = 0; i < NCHUNK; ++i) {
    const size_t o = base + (size_t)i * D_INNER;
    carry[o] = h;                 // h entering chunk i
    h = cA[o] * h + cB[o];
  }
}

// ---------------- pass C: apply carry, gate by silu(z), -> bf16 ----------------
__global__ void __launch_bounds__(256)
scan_c_kernel(const float* __restrict__ a, const u16* __restrict__ xc,
              const u16* __restrict__ sz, const float* __restrict__ carry,
              u16* __restrict__ yg) {
  const int c   = blockIdx.x * 256 + threadIdx.x;
  const int ch  = blockIdx.y;
  const int bat = blockIdx.z;
  float h = carry[((size_t)bat * NCHUNK + ch) * D_INNER + c];
  size_t idx = ((size_t)bat * LSEQ + (size_t)ch * CHUNK) * D_INNER + c;
  for (int t = 0; t < CHUNK; ++t) {
    const float av = a[idx];
    const float bv = (1.0f - av) * bf2f(xc[idx]);
    h = av * h + bv;
    yg[idx] = f2bf(h * bf2f(sz[idx]));
    idx += D_INNER;
  }
}

extern "C" void kernel_launch(void* const* d_in, const int* in_sizes, int n_in,
                              void* d_out, int out_size, void* d_ws, size_t ws_size,
                              hipStream_t stream) {
  const float* x         = (const float*)d_in[0];
  const float* norm_w    = (const float*)d_in[1];
  const float* norm_b    = (const float*)d_in[2];
  const float* in_proj_w = (const float*)d_in[3];
  const float* conv_w    = (const float*)d_in[4];
  const float* conv_b    = (const float*)d_in[5];
  const float* gate_w    = (const float*)d_in[6];
  const float* gate_b    = (const float*)d_in[7];
  const float* out_proj_w= (const float*)d_in[8];
  float* out = (float*)d_out;

  char* p = (char*)d_ws;
  u16* xn      = (u16*)p; p += (size_t)M_ROWS * D_MODEL * 2;       // 16 MB
  u16* w_in    = (u16*)p; p += (size_t)2 * D_INNER * D_MODEL * 2;  // 8 MB
  u16* w_gate  = (u16*)p; p += (size_t)D_INNER * D_INNER * 2;      // 8 MB
  u16* w_out   = (u16*)p; p += (size_t)D_MODEL * D_INNER * 2;      // 4 MB
  u16* x_inner = (u16*)p; p += (size_t)M_ROWS * D_INNER * 2;       // 32 MB
  u16* szb     = (u16*)p; p += (size_t)M_ROWS * D_INNER * 2;       // 32 MB
  u16* xconv   = (u16*)p; p += (size_t)M_ROWS * D_INNER * 2;       // 32 MB
  float* a_f   = (float*)p; p += (size_t)M_ROWS * D_INNER * 4;     // 64 MB
  u16* yg      = (u16*)p; p += (size_t)M_ROWS * D_INNER * 2;       // 32 MB
  float* cA    = (float*)p; p += (size_t)BATCH * NCHUNK * D_INNER * 4;
  float* cB    = (float*)p; p += (size_t)BATCH * NCHUNK * D_INNER * 4;
  float* carry = (float*)p; p += (size_t)BATCH * NCHUNK * D_INNER * 4;
  if ((size_t)(p - (char*)d_ws) > ws_size) return;  // workspace too small

  cast_bf16_kernel<<<dim3(2 * D_INNER * D_MODEL / 4 / 256), 256, 0, stream>>>(in_proj_w, w_in, 2 * D_INNER * D_MODEL / 4);
  cast_bf16_kernel<<<dim3(D_INNER * D_INNER / 4 / 256), 256, 0, stream>>>(gate_w, w_gate, D_INNER * D_INNER / 4);
  cast_bf16_kernel<<<dim3(D_MODEL * D_INNER / 4 / 256), 256, 0, stream>>>(out_proj_w, w_out, D_MODEL * D_INNER / 4);

  ln_kernel<<<dim3(M_ROWS), 256, 0, stream>>>(x, norm_w, norm_b, xn);

  gemm_bt<0><<<dim3((M_ROWS / 128) * (2 * D_INNER / 128)), 256, 0, stream>>>(
      xn, w_in, M_ROWS, 2 * D_INNER, D_MODEL, nullptr, nullptr, x_inner, szb);

  conv_silu_kernel<<<dim3(D_INNER / 256, LSEQ / 8, BATCH), 256, 0, stream>>>(x_inner, conv_w, conv_b, xconv);

  gemm_bt<1><<<dim3((M_ROWS / 128) * (D_INNER / 128)), 256, 0, stream>>>(
      xconv, w_gate, M_ROWS, D_INNER, D_INNER, gate_b, a_f, nullptr, nullptr);

  scan_a_kernel<<<dim3(D_INNER / 256, NCHUNK, BATCH), 256, 0, stream>>>(a_f, xconv, cA, cB);
  scan_b_kernel<<<dim3(BATCH * D_INNER / 256), 256, 0, stream>>>(cA, cB, carry);
  scan_c_kernel<<<dim3(D_INNER / 256, NCHUNK, BATCH), 256, 0, stream>>>(a_f, xconv, szb, carry, yg);

  gemm_bt<2><<<dim3((M_ROWS / 128) * (D_MODEL / 128)), 256, 0, stream>>>(
      yg, w_out, M_ROWS, D_MODEL, D_INNER, x, out, nullptr, nullptr);
}

// Round 2
// 342.625 us; speedup vs baseline: 1.1370x; 1.1370x over previous
//
#include <hip/hip_runtime.h>
#include <cstdint>

#define D_MODEL 1024
#define D_INNER 2048
#define LSEQ    4096
#define BATCH   2
#define M_ROWS  (BATCH * LSEQ)   // 8192
#define CHUNK   128
#define NCHUNK  (LSEQ / CHUNK)   // 32

typedef unsigned short u16;
typedef __bf16 bf16x8 __attribute__((ext_vector_type(8)));
typedef float f32x4 __attribute__((ext_vector_type(4)));
typedef u16 u16x4 __attribute__((ext_vector_type(4)));

__device__ __forceinline__ u16 f2bf(float f) {
  union { float f; unsigned u; } x; x.f = f;
  unsigned u = x.u;
  unsigned r = (u + 0x7FFFu + ((u >> 16) & 1u)) >> 16;
  return (u16)r;
}
__device__ __forceinline__ float bf2f(u16 h) {
  union { unsigned u; float f; } x; x.u = ((unsigned)h) << 16;
  return x.f;
}
__device__ __forceinline__ float sigmoidf_(float v) { return 1.0f / (1.0f + expf(-v)); }
__device__ __forceinline__ float siluf_(float v)    { return v / (1.0f + expf(-v)); }

__device__ __forceinline__ void gl_lds16(const void* g, void* l) {
  __builtin_amdgcn_global_load_lds(
      (const __attribute__((address_space(1))) void*)g,
      (__attribute__((address_space(3))) void*)l, 16, 0, 0);
}

#define SBAR()   asm volatile("s_barrier" ::: "memory")
#define WAITV0() asm volatile("s_waitcnt vmcnt(0)" ::: "memory")
#define WAITL0() do { asm volatile("s_waitcnt lgkmcnt(0)" ::: "memory"); __builtin_amdgcn_sched_barrier(0); } while (0)

// ---------------- cast fp32 -> bf16 (vectorized) ----------------
__global__ void __launch_bounds__(256)
cast_bf16_kernel(const float* __restrict__ in, u16* __restrict__ out, int n4) {
  int i = blockIdx.x * 256 + threadIdx.x;
  if (i < n4) {
    float4 v = ((const float4*)in)[i];
    u16x4 o;
    o.x = f2bf(v.x); o.y = f2bf(v.y); o.z = f2bf(v.z); o.w = f2bf(v.w);
    ((u16x4*)out)[i] = o;
  }
}

// ---------------- LayerNorm -> bf16 ----------------
__global__ void __launch_bounds__(256)
ln_kernel(const float* __restrict__ x, const float* __restrict__ w,
          const float* __restrict__ b, u16* __restrict__ xn) {
  const int row = blockIdx.x;
  const int t = threadIdx.x;
  const float4 v = ((const float4*)(x + (size_t)row * D_MODEL))[t];
  float s  = v.x + v.y + v.z + v.w;
  float ss = v.x * v.x + v.y * v.y + v.z * v.z + v.w * v.w;
#pragma unroll
  for (int o = 32; o > 0; o >>= 1) {
    s  += __shfl_xor(s, o);
    ss += __shfl_xor(ss, o);
  }
  __shared__ float red[8];
  const int wid = t >> 6, lane = t & 63;
  if (lane == 0) { red[wid] = s; red[4 + wid] = ss; }
  __syncthreads();
  s  = red[0] + red[1] + red[2] + red[3];
  ss = red[4] + red[5] + red[6] + red[7];
  const float mu  = s * (1.0f / D_MODEL);
  const float var = ss * (1.0f / D_MODEL) - mu * mu;
  const float rs  = rsqrtf(var + 1e-5f);
  const float4 wv = ((const float4*)w)[t];
  const float4 bv = ((const float4*)b)[t];
  u16x4 o4;
  o4.x = f2bf((v.x - mu) * rs * wv.x + bv.x);
  o4.y = f2bf((v.y - mu) * rs * wv.y + bv.y);
  o4.z = f2bf((v.z - mu) * rs * wv.z + bv.z);
  o4.w = f2bf((v.w - mu) * rs * wv.w + bv.w);
  ((u16x4*)(xn + (size_t)row * D_MODEL))[t] = o4;
}

// ======== 256x256 BK=64 8-wave double-buffered GEMM, C = A(MxK) * B(NxK)^T ========
// EPI 0: split write: col<D_INNER -> x_inner bf16 ; col>=D_INNER -> silu -> sz bf16
// EPI 1: a = sigmoid(c + bias[col]) -> fp32
// EPI 2: out = c + residual[row,col] -> fp32
#define MFMA_BF16 __builtin_amdgcn_mfma_f32_16x16x32_bf16

template<int EPI>
__global__ void __launch_bounds__(512, 2)
gemm256(const u16* __restrict__ A, const u16* __restrict__ Bm,
        int M, int N, int K,
        const float* __restrict__ ef, float* __restrict__ of,
        u16* __restrict__ ob0, u16* __restrict__ ob1) {
  __shared__ __align__(1024) char lds[131072];   // [2][32KB A] + [2][32KB B]
  const int tid  = threadIdx.x;
  const int wid  = tid >> 6, lane = tid & 63;
  const int nbx  = N >> 8;
  const int nwg  = nbx * (M >> 8);
  const int bid  = blockIdx.x;
  const int cpx  = nwg >> 3;                      // nwg % 8 == 0 for all our shapes
  const int swz  = (bid & 7) * cpx + (bid >> 3);  // XCD-aware swizzle
  const int bx   = swz % nbx, by = swz / nbx;
  const size_t m0 = (size_t)by << 8, n0 = (size_t)bx << 8;

  const int wr = wid >> 2, wc = wid & 3;          // 2 x 4 wave grid; wave tile 128x64
  const size_t rb = (size_t)K * 2;                // global row bytes
  const size_t rj = (size_t)64 * rb;              // 64-row jump

  // ---- staging addressing (pre-swizzled global source, linear LDS dest) ----
  const int srow  = lane >> 3;                          // 0..7 row within wave's 8-row slab
  const int sslot = ((lane & 7) ^ srow) << 4;           // swizzled 16B slot
  const char* gA = (const char*)A  + (m0 + (size_t)(wid * 8 + srow)) * rb + sslot;
  const char* gB = (const char*)Bm + (n0 + (size_t)(wid * 8 + srow)) * rb + sslot;
  const int sdst = wid * 1024;                          // wave's LDS slab base (+i*8192)

  // ---- ds_read addressing (swizzled) ----
  const int q    = lane >> 4;
  const int r15  = lane & 15;
  const int cswz0 = (q * 16)      ^ ((lane & 7) << 4);  // kk=0
  const int cswz1 = (64 + q * 16) ^ ((lane & 7) << 4);  // kk=1
  const int paoff = (wr * 128 + r15) * 128;             // + mi*2048 + cswz
  const int pboff = (wc * 64  + r15) * 128;             // + ni*2048 + cswz

  f32x4 acc[8][4] = {};
  const int nk = K >> 6;

  // ---- prologue: stage K-tile 0 into buffer 0 ----
  {
    const char* a = gA; const char* b = gB;
#pragma unroll
    for (int i = 0; i < 4; ++i) {
      gl_lds16(a, lds + sdst + i * 8192);
      gl_lds16(b, lds + 65536 + sdst + i * 8192);
      a += rj; b += rj;
    }
  }
  WAITV0();
  SBAR();

  int kb = 128;                                   // byte col offset of tile t+1
  for (int t = 0; t < nk; ++t) {
    const int cur = t & 1;
    const char* At = lds + cur * 32768;
    const char* Bt = lds + 65536 + cur * 32768;
    char* An = lds + (cur ^ 1) * 32768;
    char* Bn = lds + 65536 + (cur ^ 1) * 32768;
    const bool pf = (t + 1 < nk);

    bf16x8 af[4][2], b0[2][2], b1[2][2];

    // ---------- phase 1: quadrant (mh=0, nh=0) ----------
    if (pf) {
      gl_lds16(gA + kb,      An + sdst);
      gl_lds16(gA + kb + rj, An + sdst + 8192);
      gl_lds16(gB + kb,      Bn + sdst);
      gl_lds16(gB + kb + rj, Bn + sdst + 8192);
    }
#pragma unroll
    for (int mi = 0; mi < 4; ++mi) {
      af[mi][0] = *(const bf16x8*)(At + paoff + mi * 2048 + cswz0);
      af[mi][1] = *(const bf16x8*)(At + paoff + mi * 2048 + cswz1);
    }
#pragma unroll
    for (int ni = 0; ni < 2; ++ni) {
      b0[ni][0] = *(const bf16x8*)(Bt + pboff + ni * 2048 + cswz0);
      b0[ni][1] = *(const bf16x8*)(Bt + pboff + ni * 2048 + cswz1);
    }
    SBAR();
    WAITL0();
    __builtin_amdgcn_s_setprio(1);
#pragma unroll
    for (int mi = 0; mi < 4; ++mi)
#pragma unroll
      for (int ni = 0; ni < 2; ++ni) {
        acc[mi][ni] = MFMA_BF16(af[mi][0], b0[ni][0], acc[mi][ni], 0, 0, 0);
        acc[mi][ni] = MFMA_BF16(af[mi][1], b0[ni][1], acc[mi][ni], 0, 0, 0);
      }
    __builtin_amdgcn_s_setprio(0);
    SBAR();

    // ---------- phase 2: quadrant (mh=0, nh=1) ----------
    if (pf) {
      gl_lds16(gA + kb + 2 * rj, An + sdst + 16384);
      gl_lds16(gA + kb + 3 * rj, An + sdst + 24576);
      gl_lds16(gB + kb + 2 * rj, Bn + sdst + 16384);
      gl_lds16(gB + kb + 3 * rj, Bn + sdst + 24576);
    }
#pragma unroll
    for (int ni = 0; ni < 2; ++ni) {
      b1[ni][0] = *(const bf16x8*)(Bt + pboff + (ni + 2) * 2048 + cswz0);
      b1[ni][1] = *(const bf16x8*)(Bt + pboff + (ni + 2) * 2048 + cswz1);
    }
    SBAR();
    WAITL0();
    __builtin_amdgcn_s_setprio(1);
#pragma unroll
    for (int mi = 0; mi < 4; ++mi)
#pragma unroll
      for (int ni = 0; ni < 2; ++ni) {
        acc[mi][ni + 2] = MFMA_BF16(af[mi][0], b1[ni][0], acc[mi][ni + 2], 0, 0, 0);
        acc[mi][ni + 2] = MFMA_BF16(af[mi][1], b1[ni][1], acc[mi][ni + 2], 0, 0, 0);
      }
    __builtin_amdgcn_s_setprio(0);
    SBAR();

    // ---------- phase 3: quadrant (mh=1, nh=0) ----------
#pragma unroll
    for (int mi = 0; mi < 4; ++mi) {
      af[mi][0] = *(const bf16x8*)(At + paoff + (mi + 4) * 2048 + cswz0);
      af[mi][1] = *(const bf16x8*)(At + paoff + (mi + 4) * 2048 + cswz1);
    }
    SBAR();
    WAITL0();
    __builtin_amdgcn_s_setprio(1);
#pragma unroll
    for (int mi = 0; mi < 4; ++mi)
#pragma unroll
      for (int ni = 0; ni < 2; ++ni) {
        acc[mi + 4][ni] = MFMA_BF16(af[mi][0], b0[ni][0], acc[mi + 4][ni], 0, 0, 0);
        acc[mi + 4][ni] = MFMA_BF16(af[mi][1], b0[ni][1], acc[mi + 4][ni], 0, 0, 0);
      }
    __builtin_amdgcn_s_setprio(0);
    SBAR();

    // ---------- phase 4: quadrant (mh=1, nh=1), no ds_reads ----------
    __builtin_amdgcn_s_setprio(1);
#pragma unroll
    for (int mi = 0; mi < 4; ++mi)
#pragma unroll
      for (int ni = 0; ni < 2; ++ni) {
        acc[mi + 4][ni + 2] = MFMA_BF16(af[mi][0], b1[ni][0], acc[mi + 4][ni + 2], 0, 0, 0);
        acc[mi + 4][ni + 2] = MFMA_BF16(af[mi][1], b1[ni][1], acc[mi + 4][ni + 2], 0, 0, 0);
      }
    __builtin_amdgcn_s_setprio(0);
    if (pf) WAITV0();   // issued 2-3 phases ago -> cheap
    SBAR();
    kb += 128;
  }

  // ---------- epilogue ----------
  const int c0 = lane & 15;
  const int r0 = (lane >> 4) << 2;
#pragma unroll
  for (int mi = 0; mi < 8; ++mi) {
#pragma unroll
    for (int ni = 0; ni < 4; ++ni) {
#pragma unroll
      for (int rg = 0; rg < 4; ++rg) {
        const size_t row = m0 + (size_t)(wr * 128 + mi * 16 + r0 + rg);
        const size_t col = n0 + (size_t)(wc * 64 + ni * 16 + c0);
        const float v = acc[mi][ni][rg];
        if (EPI == 0) {
          if (col < (size_t)D_INNER) ob0[row * D_INNER + col] = f2bf(v);
          else                       ob1[row * D_INNER + (col - D_INNER)] = f2bf(siluf_(v));
        } else if (EPI == 1) {
          of[row * (size_t)N + col] = sigmoidf_(v + ef[col]);
        } else {
          of[row * (size_t)N + col] = v + ef[row * (size_t)N + col];
        }
      }
    }
  }
}

// ---------------- causal depthwise conv (K=4) + SiLU ----------------
__global__ void __launch_bounds__(256)
conv_silu_kernel(const u16* __restrict__ xin, const float* __restrict__ cw,
                 const float* __restrict__ cb, u16* __restrict__ xc) {
  const int c   = blockIdx.x * 256 + threadIdx.x;
  const int l0  = blockIdx.y * 8;
  const int bat = blockIdx.z;
  const size_t base = ((size_t)bat * LSEQ) * D_INNER + c;
  const float w0 = cw[c * 4 + 0], w1 = cw[c * 4 + 1], w2 = cw[c * 4 + 2], w3 = cw[c * 4 + 3];
  const float bb = cb[c];
  float v[11];
#pragma unroll
  for (int i = 0; i < 11; ++i) {
    const int l = l0 - 3 + i;
    v[i] = (l >= 0) ? bf2f(xin[base + (size_t)l * D_INNER]) : 0.0f;
  }
#pragma unroll
  for (int r = 0; r < 8; ++r) {
    const float acc = bb + w0 * v[r] + w1 * v[r + 1] + w2 * v[r + 2] + w3 * v[r + 3];
    xc[base + (size_t)(l0 + r) * D_INNER] = f2bf(siluf_(acc));
  }
}

// ---------------- chunked scan: pass A ----------------
__global__ void __launch_bounds__(256)
scan_a_kernel(const float* __restrict__ a, const u16* __restrict__ xc,
              float* __restrict__ cA, float* __restrict__ cB) {
  const int c   = blockIdx.x * 256 + threadIdx.x;
  const int ch  = blockIdx.y;
  const int bat = blockIdx.z;
  size_t idx = ((size_t)bat * LSEQ + (size_t)ch * CHUNK) * D_INNER + c;
  float pA = 1.0f, hB = 0.0f;
  for (int t = 0; t < CHUNK; ++t) {
    const float av = a[idx];
    const float bv = (1.0f - av) * bf2f(xc[idx]);
    pA *= av;
    hB = av * hB + bv;
    idx += D_INNER;
  }
  const size_t o = ((size_t)bat * NCHUNK + ch) * D_INNER + c;
  cA[o] = pA; cB[o] = hB;
}

// ---------------- pass B: serial scan over chunk summaries ----------------
__global__ void __launch_bounds__(256)
scan_b_kernel(const float* __restrict__ cA, const float* __restrict__ cB,
              float* __restrict__ carry) {
  const int tid = blockIdx.x * 256 + threadIdx.x;  // BATCH*D_INNER = 4096
  const int bat = tid >> 11;
  const int c   = tid & (D_INNER - 1);
  float h = 0.0f;
  const size_t base = (size_t)bat * NCHUNK * D_INNER + c;
  for (int i = 0; i < NCHUNK; ++i) {
    const size_t o = base + (size_t)i * D_INNER;
    carry[o] = h;
    h = cA[o] * h + cB[o];
  }
}

// ---------------- pass C: apply carry, gate by silu(z), -> bf16 ----------------
__global__ void __launch_bounds__(256)
scan_c_kernel(const float* __restrict__ a, const u16* __restrict__ xc,
              const u16* __restrict__ sz, const float* __restrict__ carry,
              u16* __restrict__ yg) {
  const int c   = blockIdx.x * 256 + threadIdx.x;
  const int ch  = blockIdx.y;
  const int bat = blockIdx.z;
  float h = carry[((size_t)bat * NCHUNK + ch) * D_INNER + c];
  size_t idx = ((size_t)bat * LSEQ + (size_t)ch * CHUNK) * D_INNER + c;
  for (int t = 0; t < CHUNK; ++t) {
    const float av = a[idx];
    const float bv = (1.0f - av) * bf2f(xc[idx]);
    h = av * h + bv;
    yg[idx] = f2bf(h * bf2f(sz[idx]));
    idx += D_INNER;
  }
}

extern "C" void kernel_launch(void* const* d_in, const int* in_sizes, int n_in,
                              void* d_out, int out_size, void* d_ws, size_t ws_size,
                              hipStream_t stream) {
  const float* x         = (const float*)d_in[0];
  const float* norm_w    = (const float*)d_in[1];
  const float* norm_b    = (const float*)d_in[2];
  const float* in_proj_w = (const float*)d_in[3];
  const float* conv_w    = (const float*)d_in[4];
  const float* conv_b    = (const float*)d_in[5];
  const float* gate_w    = (const float*)d_in[6];
  const float* gate_b    = (const float*)d_in[7];
  const float* out_proj_w= (const float*)d_in[8];
  float* out = (float*)d_out;

  char* p = (char*)d_ws;
  u16* xn      = (u16*)p; p += (size_t)M_ROWS * D_MODEL * 2;
  u16* w_in    = (u16*)p; p += (size_t)2 * D_INNER * D_MODEL * 2;
  u16* w_gate  = (u16*)p; p += (size_t)D_INNER * D_INNER * 2;
  u16* w_out   = (u16*)p; p += (size_t)D_MODEL * D_INNER * 2;
  u16* x_inner = (u16*)p; p += (size_t)M_ROWS * D_INNER * 2;
  u16* szb     = (u16*)p; p += (size_t)M_ROWS * D_INNER * 2;
  u16* xconv   = (u16*)p; p += (size_t)M_ROWS * D_INNER * 2;
  float* a_f   = (float*)p; p += (size_t)M_ROWS * D_INNER * 4;
  u16* yg      = (u16*)p; p += (size_t)M_ROWS * D_INNER * 2;
  float* cA    = (float*)p; p += (size_t)BATCH * NCHUNK * D_INNER * 4;
  float* cB    = (float*)p; p += (size_t)BATCH * NCHUNK * D_INNER * 4;
  float* carry = (float*)p; p += (size_t)BATCH * NCHUNK * D_INNER * 4;
  if ((size_t)(p - (char*)d_ws) > ws_size) return;

  cast_bf16_kernel<<<dim3(2 * D_INNER * D_MODEL / 4 / 256), 256, 0, stream>>>(in_proj_w, w_in, 2 * D_INNER * D_MODEL / 4);
  cast_bf16_kernel<<<dim3(D_INNER * D_INNER / 4 / 256), 256, 0, stream>>>(gate_w, w_gate, D_INNER * D_INNER / 4);
  cast_bf16_kernel<<<dim3(D_MODEL * D_INNER / 4 / 256), 256, 0, stream>>>(out_proj_w, w_out, D_MODEL * D_INNER / 4);

  ln_kernel<<<dim3(M_ROWS), 256, 0, stream>>>(x, norm_w, norm_b, xn);

  gemm256<0><<<dim3((M_ROWS / 256) * (2 * D_INNER / 256)), 512, 0, stream>>>(
      xn, w_in, M_ROWS, 2 * D_INNER, D_MODEL, nullptr, nullptr, x_inner, szb);

  conv_silu_kernel<<<dim3(D_INNER / 256, LSEQ / 8, BATCH), 256, 0, stream>>>(x_inner, conv_w, conv_b, xconv);

  gemm256<1><<<dim3((M_ROWS / 256) * (D_INNER / 256)), 512, 0, stream>>>(
      xconv, w_gate, M_ROWS, D_INNER, D_INNER, gate_b, a_f, nullptr, nullptr);

  scan_a_kernel<<<dim3(D_INNER / 256, NCHUNK, BATCH), 256, 0, stream>>>(a_f, xconv, cA, cB);
  scan_b_kernel<<<dim3(BATCH * D_INNER / 256), 256, 0, stream>>>(cA, cB, carry);
  scan_c_kernel<<<dim3(D_INNER / 256, NCHUNK, BATCH), 256, 0, stream>>>(a_f, xconv, szb, carry, yg);

  gemm256<2><<<dim3((M_ROWS / 256) * (D_MODEL / 256)), 512, 0, stream>>>(
      yg, w_out, M_ROWS, D_MODEL, D_INNER, x, out, nullptr, nullptr);
}